// Round 1
// baseline (274.261 us; speedup 1.0000x reference)
//
#include <hip/hip_runtime.h>
#include <math.h>

#define ADIM 256
#define ODIM 80
#define NB 4
#define TTEXT 160
#define TFEAT 800

// ---------------------------------------------------------------------------
// lgamma table for integers 0..1023 (we use 1..961). Double-precision lgamma
// on device -> float table. Prior args are all integers so this is exact
// enough (abs err ~1e-5 on values up to ~5600).
// ---------------------------------------------------------------------------
__global__ void lgamma_table_kernel(float* __restrict__ lg) {
    int n = threadIdx.x;  // 0..1023
    lg[n] = (n >= 1) ? (float)lgamma((double)n) : 0.0f;
}

// ---------------------------------------------------------------------------
// Generic conv1d, cross-correlation, 'same' padding for K=3, none for K=1.
// in:  (B, T, CIN)   w: (256, CIN, K)   bias: (256)   out: (B, T, 256)
// One block = one (batch, 16-wide time tile); 256 threads = output channels.
// Input rows staged in LDS (broadcast reads, conflict-free); weights are
// per-thread sequential (L1/L2 cached, reused TILE times in registers).
// ---------------------------------------------------------------------------
template<int CIN, int K, bool RELU, int TILE>
__global__ __launch_bounds__(256) void conv1d_kernel(
        const float* __restrict__ in, int T,
        const float* __restrict__ w, const float* __restrict__ bias,
        float* __restrict__ out) {
    constexpr int PAD = (K - 1) / 2;
    constexpr int NROWS = TILE + K - 1;
    const int co = threadIdx.x;
    const int x0 = blockIdx.x * TILE;
    const int b = blockIdx.y;

    __shared__ float s_in[NROWS * CIN];
    for (int idx = threadIdx.x; idx < NROWS * CIN; idx += 256) {
        int r = idx / CIN;
        int c = idx - r * CIN;
        int x = x0 - PAD + r;
        s_in[idx] = (x >= 0 && x < T) ? in[((long)b * T + x) * CIN + c] : 0.0f;
    }
    __syncthreads();

    float acc[TILE];
    const float bv = bias[co];
#pragma unroll
    for (int i = 0; i < TILE; ++i) acc[i] = bv;

    const float* wp = w + (long)co * CIN * K;
    for (int ci = 0; ci < CIN; ++ci) {
#pragma unroll
        for (int k = 0; k < K; ++k) {
            float wv = wp[ci * K + k];
#pragma unroll
            for (int i = 0; i < TILE; ++i)
                acc[i] = fmaf(wv, s_in[(i + k) * CIN + ci], acc[i]);
        }
    }

#pragma unroll
    for (int i = 0; i < TILE; ++i) {
        int x = x0 + i;
        if (x < T) {
            float v = acc[i];
            if (RELU) v = fmaxf(v, 0.0f);
            out[((long)b * T + x) * ADIM + co] = v;
        }
    }
}

// ---------------------------------------------------------------------------
// Score + log_softmax + beta-binomial prior, fused.
// f: (B, TFEAT, 256)  t: (B, TTEXT, 256)  out: (B, TFEAT, TTEXT)
// One block per (b, feats-row i). Threads j<160 each compute one score.
// prior(i,j) = lg(801)-lg(i+1)-lg(801-i)+lg(i+j+1)+lg(960-i-j)
//              -lg(961)-lg(j+1)-lg(160-j)+lg(161)
// ---------------------------------------------------------------------------
__global__ __launch_bounds__(256) void score_kernel(
        const float* __restrict__ f, const float* __restrict__ t,
        const unsigned char* __restrict__ xmask,
        const float* __restrict__ lg, float* __restrict__ out) {
    const int i = blockIdx.x;   // feats row
    const int b = blockIdx.y;
    const int tid = threadIdx.x;

    __shared__ float s_f[ADIM];
    __shared__ float s_red[256];

    s_f[tid] = f[((long)b * TFEAT + i) * ADIM + tid];
    __syncthreads();

    float sc = -INFINITY;
    if (tid < TTEXT) {
        const float* tp = t + ((long)b * TTEXT + tid) * ADIM;
        float a0 = 0.f, a1 = 0.f, a2 = 0.f, a3 = 0.f;
        for (int d = 0; d < ADIM; d += 4) {
            float4 tv = *reinterpret_cast<const float4*>(tp + d);
            float d0 = s_f[d + 0] - tv.x;
            float d1 = s_f[d + 1] - tv.y;
            float d2 = s_f[d + 2] - tv.z;
            float d3 = s_f[d + 3] - tv.w;
            a0 = fmaf(d0, d0, a0);
            a1 = fmaf(d1, d1, a1);
            a2 = fmaf(d2, d2, a2);
            a3 = fmaf(d3, d3, a3);
        }
        sc = -sqrtf((a0 + a1) + (a2 + a3));
        if (xmask[b * TTEXT + tid]) sc = -INFINITY;
    }

    // block max over the 160 valid scores
    s_red[tid] = (tid < TTEXT) ? sc : -INFINITY;
    __syncthreads();
    for (int s = 128; s > 0; s >>= 1) {
        if (tid < s) s_red[tid] = fmaxf(s_red[tid], s_red[tid + s]);
        __syncthreads();
    }
    const float m = s_red[0];
    __syncthreads();

    float e = (tid < TTEXT) ? expf(sc - m) : 0.0f;
    s_red[tid] = e;
    __syncthreads();
    for (int s = 128; s > 0; s >>= 1) {
        if (tid < s) s_red[tid] += s_red[tid + s];
        __syncthreads();
    }
    const float lsum = logf(s_red[0]);

    if (tid < TTEXT) {
        const int j = tid;
        float prior = lg[801] - lg[i + 1] - lg[801 - i]
                    + lg[i + j + 1] + lg[960 - i - j]
                    - lg[961] - lg[j + 1] - lg[160 - j] + lg[161];
        out[((long)b * TFEAT + i) * TTEXT + j] = sc - m - lsum + prior;
    }
}

extern "C" void kernel_launch(void* const* d_in, const int* in_sizes, int n_in,
                              void* d_out, int out_size, void* d_ws, size_t ws_size,
                              hipStream_t stream) {
    const float* text  = (const float*)d_in[0];   // (4,160,256)
    const float* feats = (const float*)d_in[1];   // (4,800,80)
    // d_in[2]/d_in[3]: lengths (unused; lengths == max in this problem)
    const unsigned char* xmask = (const unsigned char*)d_in[4]; // (4,160) bool
    const float* t_w1 = (const float*)d_in[5];
    const float* t_b1 = (const float*)d_in[6];
    const float* t_w2 = (const float*)d_in[7];
    const float* t_b2 = (const float*)d_in[8];
    const float* f_w1 = (const float*)d_in[9];
    const float* f_b1 = (const float*)d_in[10];
    const float* f_w2 = (const float*)d_in[11];
    const float* f_b2 = (const float*)d_in[12];
    const float* f_w3 = (const float*)d_in[13];
    const float* f_b3 = (const float*)d_in[14];
    float* out = (float*)d_out;

    float* ws = (float*)d_ws;
    float* lg = ws;                        // 1024 floats
    float* tA = lg + 1024;                 // (4,160,256)
    float* tB = tA + NB * TTEXT * ADIM;    // (4,160,256)
    float* fA = tB + NB * TTEXT * ADIM;    // (4,800,256)
    float* fB = fA + NB * TFEAT * ADIM;    // (4,800,256)
    float* fC = fB + NB * TFEAT * ADIM;    // (4,800,256)

    lgamma_table_kernel<<<1, 1024, 0, stream>>>(lg);

    // text stem
    conv1d_kernel<ADIM, 3, true, 16><<<dim3(TTEXT / 16, NB), 256, 0, stream>>>(
        text, TTEXT, t_w1, t_b1, tA);
    conv1d_kernel<ADIM, 1, false, 16><<<dim3(TTEXT / 16, NB), 256, 0, stream>>>(
        tA, TTEXT, t_w2, t_b2, tB);

    // feats stem
    conv1d_kernel<ODIM, 3, true, 16><<<dim3(TFEAT / 16, NB), 256, 0, stream>>>(
        feats, TFEAT, f_w1, f_b1, fA);
    conv1d_kernel<ADIM, 3, true, 16><<<dim3(TFEAT / 16, NB), 256, 0, stream>>>(
        fA, TFEAT, f_w2, f_b2, fB);
    conv1d_kernel<ADIM, 1, false, 16><<<dim3(TFEAT / 16, NB), 256, 0, stream>>>(
        fB, TFEAT, f_w3, f_b3, fC);

    // fused score + log_softmax + prior
    score_kernel<<<dim3(TFEAT, NB), 256, 0, stream>>>(fC, tB, xmask, lg, out);
}

// Round 2
// 143.282 us; speedup vs baseline: 1.9141x; 1.9141x over previous
//
#include <hip/hip_runtime.h>
#include <math.h>

#define NB 4
#define TTEXT 160
#define TFEAT 800

typedef __bf16 bf16x8 __attribute__((ext_vector_type(8)));
typedef float f32x4 __attribute__((ext_vector_type(4)));
typedef unsigned short us8 __attribute__((ext_vector_type(8)));

__device__ inline unsigned short f2bf(float f) {
    unsigned int u = __builtin_bit_cast(unsigned int, f);
    unsigned int r = u + 0x7fffu + ((u >> 16) & 1u);
    return (unsigned short)(r >> 16);
}
__device__ inline float bf2f(unsigned short h) {
    unsigned int u = ((unsigned int)h) << 16;
    return __builtin_bit_cast(float, u);
}

// ---------------------------------------------------------------------------
// Prep: 5 weight transforms into B-fragment-native layout Wb[c][co][q]
// (q = 0..31 contiguous k-slice per output channel, chunk c of 32 along
// K-dim = K*CINP), plus the integer lgamma table.
// ---------------------------------------------------------------------------
__global__ __launch_bounds__(256) void prep_kernel(
    const float* __restrict__ tw1, const float* __restrict__ tw2,
    const float* __restrict__ fw1, const float* __restrict__ fw2,
    const float* __restrict__ fw3,
    unsigned short* __restrict__ wb_t1, unsigned short* __restrict__ wb_t2,
    unsigned short* __restrict__ wb_f1, unsigned short* __restrict__ wb_f2,
    unsigned short* __restrict__ wb_f3, float* __restrict__ lg)
{
    const int layer = blockIdx.y;
    const int idx = blockIdx.x * 256 + threadIdx.x;
    if (layer == 5) {
        if (idx < 1024) lg[idx] = (idx >= 1) ? (float)lgamma((double)idx) : 0.0f;
        return;
    }
    int CIN, CINP, K; const float* src; unsigned short* dst;
    switch (layer) {
        case 0:  CIN = 256; CINP = 256; K = 3; src = tw1; dst = wb_t1; break;
        case 1:  CIN = 256; CINP = 256; K = 1; src = tw2; dst = wb_t2; break;
        case 2:  CIN = 80;  CINP = 96;  K = 3; src = fw1; dst = wb_f1; break;
        case 3:  CIN = 256; CINP = 256; K = 3; src = fw2; dst = wb_f2; break;
        default: CIN = 256; CINP = 256; K = 1; src = fw3; dst = wb_f3; break;
    }
    const int total = CINP * K * 256;
    if (idx >= total) return;
    const int q  = idx & 31;
    const int coc = idx >> 5;
    const int co = coc & 255;
    const int c  = coc >> 8;
    const int cpk = CINP / 32;
    const int k  = c / cpk;
    const int ci = (c % cpk) * 32 + q;
    float v = (ci < CIN) ? src[((size_t)co * CIN + ci) * K + k] : 0.0f;
    dst[idx] = f2bf(v);
}

// ---------------------------------------------------------------------------
// Conv1d as implicit-im2col MFMA GEMM.  Block = 256 thr (4 waves), tile
// M=64 time steps x N=256 channels (wave w owns cols w*64..+64).
// No LDS / no barriers in the main loop: A-frags read (+convert) straight
// from global per lane (L1 serves the 4x cross-wave reuse); B-frags are
// contiguous 16B lane-reads from the pre-transposed weight buffer.
// Optional epilogue: store bf16 activation + row ||.||^2 (of the ROUNDED
// values, so the later distance is exactly consistent).
// ---------------------------------------------------------------------------
template<int CIN, int CINP, int K, int T, bool RELU, bool NORM, bool IN_F32>
__global__ __launch_bounds__(256) void conv_mfma(
    const void* __restrict__ in_, const unsigned short* __restrict__ Wb,
    const float* __restrict__ bias, unsigned short* __restrict__ out,
    float* __restrict__ norm)
{
    constexpr int PAD = (K - 1) / 2;
    constexpr int CPK = CINP / 32;
    constexpr int CHUNKS = CPK * K;
    const int b  = blockIdx.y;
    const int t0 = blockIdx.x * 64;
    const int tid = threadIdx.x;
    const int w  = tid >> 6;
    const int l  = tid & 63;
    const int lr = l & 15;
    const int lk = l >> 4;
    const int co0 = w * 64;

    const float* __restrict__ inF = (const float*)in_;
    const unsigned short* __restrict__ inH = (const unsigned short*)in_;

    f32x4 acc[4][4];
#pragma unroll
    for (int m = 0; m < 4; ++m)
#pragma unroll
        for (int n = 0; n < 4; ++n) acc[m][n] = {0.f, 0.f, 0.f, 0.f};

#pragma unroll 2
    for (int c = 0; c < CHUNKS; ++c) {
        const int k  = c / CPK;
        const int ci = (c % CPK) * 32 + lk * 8;
        bf16x8 a[4];
#pragma unroll
        for (int m = 0; m < 4; ++m) {
            const int trow = t0 + m * 16 + lr + k - PAD;
            us8 av = {0, 0, 0, 0, 0, 0, 0, 0};
            if (trow >= 0 && trow < T && ci < CIN) {
                if (IN_F32) {
                    const float* p = inF + ((size_t)(b * T + trow)) * CIN + ci;
                    float4 u0 = *(const float4*)p;
                    float4 u1 = *(const float4*)(p + 4);
                    av[0] = f2bf(u0.x); av[1] = f2bf(u0.y);
                    av[2] = f2bf(u0.z); av[3] = f2bf(u0.w);
                    av[4] = f2bf(u1.x); av[5] = f2bf(u1.y);
                    av[6] = f2bf(u1.z); av[7] = f2bf(u1.w);
                } else {
                    av = *(const us8*)(inH + ((size_t)(b * T + trow)) * CIN + ci);
                }
            }
            a[m] = __builtin_bit_cast(bf16x8, av);
        }
#pragma unroll
        for (int n = 0; n < 4; ++n) {
            const int co = co0 + n * 16 + lr;
            bf16x8 bfr = *(const bf16x8*)(Wb + ((size_t)(c * 256 + co)) * 32 + lk * 8);
#pragma unroll
            for (int m = 0; m < 4; ++m)
                acc[m][n] = __builtin_amdgcn_mfma_f32_16x16x32_bf16(a[m], bfr, acc[m][n], 0, 0, 0);
        }
    }

    __shared__ float s_norm[64][4];

    float bv[4];
#pragma unroll
    for (int n = 0; n < 4; ++n) bv[n] = bias[co0 + n * 16 + lr];

#pragma unroll
    for (int m = 0; m < 4; ++m) {
#pragma unroll
        for (int r = 0; r < 4; ++r) {
            const int row = t0 + m * 16 + lk * 4 + r;
            float np_ = 0.f;
#pragma unroll
            for (int n = 0; n < 4; ++n) {
                float v = acc[m][n][r] + bv[n];
                if (RELU) v = fmaxf(v, 0.0f);
                const unsigned short h = f2bf(v);
                if (row < T)
                    out[((size_t)(b * T + row)) * 256 + co0 + n * 16 + lr] = h;
                if (NORM) { float vq = bf2f(h); np_ = fmaf(vq, vq, np_); }
            }
            if (NORM) {
                np_ += __shfl_xor(np_, 1);
                np_ += __shfl_xor(np_, 2);
                np_ += __shfl_xor(np_, 4);
                np_ += __shfl_xor(np_, 8);
                if (lr == 0) s_norm[m * 16 + lk * 4 + r][w] = np_;
            }
        }
    }
    if (NORM) {
        __syncthreads();
        if (tid < 64 && t0 + tid < T) {
            float s = s_norm[tid][0] + s_norm[tid][1] + s_norm[tid][2] + s_norm[tid][3];
            norm[b * T + t0 + tid] = s;
        }
    }
}

// ---------------------------------------------------------------------------
// Score = -sqrt(||f||^2+||t||^2-2 f.t) + log_softmax + beta-binomial prior,
// with f.t as an MFMA GEMM (M=800 feats rows, N=160 text cols, K=256).
// Each wave owns 16 complete output rows (1 M-frag x 10 N-frags) so the
// softmax is a pure 16-lane shfl reduction; no LDS, no barriers.
// ---------------------------------------------------------------------------
__global__ __launch_bounds__(256) void score_mfma(
    const unsigned short* __restrict__ F, const unsigned short* __restrict__ Tt,
    const float* __restrict__ fnorm, const float* __restrict__ tnorm,
    const unsigned char* __restrict__ xmask, const float* __restrict__ lg,
    float* __restrict__ out)
{
    const int b  = blockIdx.y;
    const int tid = threadIdx.x;
    const int w  = tid >> 6;
    const int l  = tid & 63;
    const int lr = l & 15;
    const int lk = l >> 4;
    const int i0 = blockIdx.x * 64 + w * 16;

    f32x4 acc[10];
#pragma unroll
    for (int n = 0; n < 10; ++n) acc[n] = {0.f, 0.f, 0.f, 0.f};

    const int arow = i0 + lr;
    const bool avalid = arow < TFEAT;
    const unsigned short* __restrict__ Fp = F + ((size_t)(b * TFEAT + arow)) * 256;
    const unsigned short* __restrict__ Tp = Tt + ((size_t)b * TTEXT) * 256;

#pragma unroll 2
    for (int c = 0; c < 8; ++c) {
        const int d = c * 32 + lk * 8;
        us8 av = {0, 0, 0, 0, 0, 0, 0, 0};
        if (avalid) av = *(const us8*)(Fp + d);
        const bf16x8 a = __builtin_bit_cast(bf16x8, av);
#pragma unroll
        for (int n = 0; n < 10; ++n) {
            bf16x8 bfr = *(const bf16x8*)(Tp + ((size_t)(n * 16 + lr)) * 256 + d);
            acc[n] = __builtin_amdgcn_mfma_f32_16x16x32_bf16(a, bfr, acc[n], 0, 0, 0);
        }
    }

    // --- epilogue: distances ---
    float fn[4];
#pragma unroll
    for (int r = 0; r < 4; ++r) {
        const int row = i0 + lk * 4 + r;
        fn[r] = (row < TFEAT) ? fnorm[b * TFEAT + row] : 0.f;
    }
    float tn[10]; bool mk[10];
#pragma unroll
    for (int n = 0; n < 10; ++n) {
        const int j = n * 16 + lr;
        tn[n] = tnorm[b * TTEXT + j];
        mk[n] = xmask[b * TTEXT + j] != 0;
    }
    float sc[10][4];
#pragma unroll
    for (int n = 0; n < 10; ++n)
#pragma unroll
        for (int r = 0; r < 4; ++r) {
            float d2 = fn[r] + tn[n] - 2.0f * acc[n][r];
            float s = -sqrtf(fmaxf(d2, 0.0f));
            sc[n][r] = mk[n] ? -INFINITY : s;
        }

    // --- log-softmax per row (16 lanes x 10 frags hold one row) ---
    const float cst = lg[161] - lg[961] + lg[801];
#pragma unroll
    for (int r = 0; r < 4; ++r) {
        float mx = sc[0][r];
#pragma unroll
        for (int n = 1; n < 10; ++n) mx = fmaxf(mx, sc[n][r]);
        mx = fmaxf(mx, __shfl_xor(mx, 1));
        mx = fmaxf(mx, __shfl_xor(mx, 2));
        mx = fmaxf(mx, __shfl_xor(mx, 4));
        mx = fmaxf(mx, __shfl_xor(mx, 8));
        float s = 0.f;
#pragma unroll
        for (int n = 0; n < 10; ++n) s += expf(sc[n][r] - mx);
        s += __shfl_xor(s, 1);
        s += __shfl_xor(s, 2);
        s += __shfl_xor(s, 4);
        s += __shfl_xor(s, 8);
        const float lse = mx + logf(s);

        const int row = i0 + lk * 4 + r;
        if (row >= TFEAT) continue;
        const float rowterm = cst - lg[row + 1] - lg[801 - row];
#pragma unroll
        for (int n = 0; n < 10; ++n) {
            const int j = n * 16 + lr;
            const float prior = rowterm - lg[j + 1] - lg[160 - j]
                              + lg[row + j + 1] + lg[960 - row - j];
            out[((size_t)(b * TFEAT + row)) * TTEXT + j] = sc[n][r] - lse + prior;
        }
    }
}

extern "C" void kernel_launch(void* const* d_in, const int* in_sizes, int n_in,
                              void* d_out, int out_size, void* d_ws, size_t ws_size,
                              hipStream_t stream) {
    const float* text  = (const float*)d_in[0];
    const float* feats = (const float*)d_in[1];
    const unsigned char* xmask = (const unsigned char*)d_in[4];
    const float* t_w1 = (const float*)d_in[5];
    const float* t_b1 = (const float*)d_in[6];
    const float* t_w2 = (const float*)d_in[7];
    const float* t_b2 = (const float*)d_in[8];
    const float* f_w1 = (const float*)d_in[9];
    const float* f_b1 = (const float*)d_in[10];
    const float* f_w2 = (const float*)d_in[11];
    const float* f_b2 = (const float*)d_in[12];
    const float* f_w3 = (const float*)d_in[13];
    const float* f_b3 = (const float*)d_in[14];
    float* out = (float*)d_out;

    char* wp = (char*)d_ws;
    auto alloc = [&](size_t bytes) -> void* {
        void* p = wp; wp += (bytes + 255) & ~(size_t)255; return p;
    };
    float* lg = (float*)alloc(1024 * 4);
    unsigned short* wb_t1 = (unsigned short*)alloc(196608 * 2);
    unsigned short* wb_t2 = (unsigned short*)alloc(65536 * 2);
    unsigned short* wb_f1 = (unsigned short*)alloc(73728 * 2);
    unsigned short* wb_f2 = (unsigned short*)alloc(196608 * 2);
    unsigned short* wb_f3 = (unsigned short*)alloc(65536 * 2);
    unsigned short* tA = (unsigned short*)alloc((size_t)NB * TTEXT * 256 * 2);
    unsigned short* tB = (unsigned short*)alloc((size_t)NB * TTEXT * 256 * 2);
    unsigned short* fA = (unsigned short*)alloc((size_t)NB * TFEAT * 256 * 2);
    unsigned short* fB = (unsigned short*)alloc((size_t)NB * TFEAT * 256 * 2);
    unsigned short* fC = (unsigned short*)alloc((size_t)NB * TFEAT * 256 * 2);
    float* fnorm = (float*)alloc((size_t)NB * TFEAT * 4);
    float* tnorm = (float*)alloc((size_t)NB * TTEXT * 4);

    prep_kernel<<<dim3(768, 6), 256, 0, stream>>>(
        t_w1, t_w2, f_w1, f_w2, f_w3, wb_t1, wb_t2, wb_f1, wb_f2, wb_f3, lg);

    // text stem
    conv_mfma<256, 256, 3, TTEXT, true,  false, true ><<<dim3(3, NB), 256, 0, stream>>>(
        text, wb_t1, t_b1, tA, nullptr);
    conv_mfma<256, 256, 1, TTEXT, false, true,  false><<<dim3(3, NB), 256, 0, stream>>>(
        tA, wb_t2, t_b2, tB, tnorm);

    // feats stem
    conv_mfma<80,  96,  3, TFEAT, true,  false, true ><<<dim3(13, NB), 256, 0, stream>>>(
        feats, wb_f1, f_b1, fA, nullptr);
    conv_mfma<256, 256, 3, TFEAT, true,  false, false><<<dim3(13, NB), 256, 0, stream>>>(
        fA, wb_f2, f_b2, fB, nullptr);
    conv_mfma<256, 256, 1, TFEAT, false, true,  false><<<dim3(13, NB), 256, 0, stream>>>(
        fB, wb_f3, f_b3, fC, fnorm);

    // fused distance + log_softmax + prior
    score_mfma<<<dim3(13, NB), 256, 0, stream>>>(fC, tB, fnorm, tnorm, xmask, lg, out);
}

// Round 3
// 47.875 us; speedup vs baseline: 5.7287x; 2.9929x over previous
//
#include <hip/hip_runtime.h>
#include <math.h>

#define NB 4
#define TTEXT 160
#define TFEAT 800

typedef __bf16 bf16x8 __attribute__((ext_vector_type(8)));
typedef float f32x4 __attribute__((ext_vector_type(4)));
typedef unsigned short us8 __attribute__((ext_vector_type(8)));

__device__ inline unsigned short f2bf(float f) {
    unsigned int u = __builtin_bit_cast(unsigned int, f);
    unsigned int r = u + 0x7fffu + ((u >> 16) & 1u);
    return (unsigned short)(r >> 16);
}
__device__ inline float bf2f(unsigned short h) {
    unsigned int u = ((unsigned int)h) << 16;
    return __builtin_bit_cast(float, u);
}
__device__ inline bf16x8 mfma_cast(us8 v) { return __builtin_bit_cast(bf16x8, v); }

// ---------------------------------------------------------------------------
// Prep: weight transforms into B-fragment-native layout Wb[c][co][q] + lgamma
// table (identical logic to the verified round-2 version).
// ---------------------------------------------------------------------------
__global__ __launch_bounds__(256) void prep_kernel(
    const float* __restrict__ tw1, const float* __restrict__ tw2,
    const float* __restrict__ fw1, const float* __restrict__ fw2,
    const float* __restrict__ fw3,
    unsigned short* __restrict__ wb_t1, unsigned short* __restrict__ wb_t2,
    unsigned short* __restrict__ wb_f1, unsigned short* __restrict__ wb_f2,
    unsigned short* __restrict__ wb_f3, float* __restrict__ lg)
{
    const int layer = blockIdx.y;
    const int idx = blockIdx.x * 256 + threadIdx.x;
    if (layer == 5) {
        if (idx < 1024) lg[idx] = (idx >= 1) ? (float)lgamma((double)idx) : 0.0f;
        return;
    }
    int CIN, CINP, K; const float* src; unsigned short* dst;
    switch (layer) {
        case 0:  CIN = 256; CINP = 256; K = 3; src = tw1; dst = wb_t1; break;
        case 1:  CIN = 256; CINP = 256; K = 1; src = tw2; dst = wb_t2; break;
        case 2:  CIN = 80;  CINP = 96;  K = 3; src = fw1; dst = wb_f1; break;
        case 3:  CIN = 256; CINP = 256; K = 3; src = fw2; dst = wb_f2; break;
        default: CIN = 256; CINP = 256; K = 1; src = fw3; dst = wb_f3; break;
    }
    const int total = CINP * K * 256;
    if (idx >= total) return;
    const int q   = idx & 31;
    const int coc = idx >> 5;
    const int co  = coc & 255;
    const int c   = coc >> 8;
    const int cpk = CINP / 32;
    const int k   = c / cpk;
    const int ci  = (c % cpk) * 32 + q;
    float v = (ci < CIN) ? src[((size_t)co * CIN + ci) * K + k] : 0.0f;
    dst[idx] = f2bf(v);
}

// ---------------------------------------------------------------------------
// Fused stems. Block = 256 thr (4 waves, wave w owns 64 output channels).
// bid < 40  : text tile  (b = bid&3, 16 rows) : stage 18 rows -> t1(K3) -> LDS
//             -> t2(K1) -> tB + tnorm
// bid >= 40 : feats tile (200 blocks, 16 rows): stage 20 rows -> f1(K3, 18
//             rows incl. halo) -> LDS -> f2(K3) -> LDS -> f3(K1) -> fC + fnorm
// All LDS row strides padded (264 / 104 elems) -> 2-way bank alias (free).
// Norms computed from bf16-ROUNDED stored activations for exact consistency
// with the score kernel's distance expansion.
// ---------------------------------------------------------------------------
__global__ __launch_bounds__(256) void stems_kernel(
    const float* __restrict__ text, const float* __restrict__ feats,
    const unsigned short* __restrict__ wt1, const float* __restrict__ bt1,
    const unsigned short* __restrict__ wt2, const float* __restrict__ bt2,
    const unsigned short* __restrict__ wf1, const float* __restrict__ bf1v,
    const unsigned short* __restrict__ wf2, const float* __restrict__ bf2v,
    const unsigned short* __restrict__ wf3, const float* __restrict__ bf3v,
    unsigned short* __restrict__ tB, float* __restrict__ tnorm,
    unsigned short* __restrict__ fC, float* __restrict__ fnorm)
{
    __shared__ __align__(16) unsigned short s[11056];
    __shared__ float s_red[16][4];
    const int tid = threadIdx.x;
    const int w  = tid >> 6;
    const int l  = tid & 63;
    const int lr = l & 15;
    const int lk = l >> 4;
    const int co0 = w * 64;
    const int koff = lk * 8;
    const int bid = blockIdx.x;

    if (bid < 40) {
        // ------------------------- text stem -------------------------
        const int b  = bid & 3;
        const int t0 = (bid >> 2) << 4;
        unsigned short* s_in  = s;          // [18][264]
        unsigned short* s_mid = s + 4752;   // [16][264]

        for (int idx = tid; idx < 18 * 64; idx += 256) {
            const int r = idx >> 6, c4 = idx & 63;
            const int x = t0 - 1 + r;
            float4 v = {0.f, 0.f, 0.f, 0.f};
            if (x >= 0 && x < TTEXT)
                v = *(const float4*)(text + ((size_t)(b * TTEXT + x)) * 256 + c4 * 4);
            unsigned short* p = s_in + r * 264 + c4 * 4;
            p[0] = f2bf(v.x); p[1] = f2bf(v.y); p[2] = f2bf(v.z); p[3] = f2bf(v.w);
        }
        __syncthreads();

        // t1: K=3, CIN=256 -> 24 chunks
        f32x4 acc[4];
#pragma unroll
        for (int n = 0; n < 4; ++n) acc[n] = {0.f, 0.f, 0.f, 0.f};
#pragma unroll 4
        for (int c = 0; c < 24; ++c) {
            const int k  = c >> 3;
            const int ci = ((c & 7) << 5) + koff;
            const bf16x8 a = *(const bf16x8*)(s_in + (lr + k) * 264 + ci);
#pragma unroll
            for (int n = 0; n < 4; ++n) {
                const bf16x8 bb = *(const bf16x8*)(wt1 + (((size_t)c * 256 + co0 + n * 16 + lr) << 5) + koff);
                acc[n] = __builtin_amdgcn_mfma_f32_16x16x32_bf16(a, bb, acc[n], 0, 0, 0);
            }
        }
#pragma unroll
        for (int n = 0; n < 4; ++n) {
            const float bv = bt1[co0 + n * 16 + lr];
#pragma unroll
            for (int r = 0; r < 4; ++r)
                s_mid[(lk * 4 + r) * 264 + co0 + n * 16 + lr] = f2bf(fmaxf(acc[n][r] + bv, 0.f));
        }
        __syncthreads();

        // t2: K=1 -> 8 chunks, epilogue to global + norm
        f32x4 a2[4];
#pragma unroll
        for (int n = 0; n < 4; ++n) a2[n] = {0.f, 0.f, 0.f, 0.f};
#pragma unroll
        for (int c = 0; c < 8; ++c) {
            const bf16x8 a = *(const bf16x8*)(s_mid + lr * 264 + (c << 5) + koff);
#pragma unroll
            for (int n = 0; n < 4; ++n) {
                const bf16x8 bb = *(const bf16x8*)(wt2 + (((size_t)c * 256 + co0 + n * 16 + lr) << 5) + koff);
                a2[n] = __builtin_amdgcn_mfma_f32_16x16x32_bf16(a, bb, a2[n], 0, 0, 0);
            }
        }
        float bv2[4];
#pragma unroll
        for (int n = 0; n < 4; ++n) bv2[n] = bt2[co0 + n * 16 + lr];
#pragma unroll
        for (int r = 0; r < 4; ++r) {
            const int row = lk * 4 + r;
            float np = 0.f;
#pragma unroll
            for (int n = 0; n < 4; ++n) {
                const unsigned short h = f2bf(a2[n][r] + bv2[n]);
                tB[((size_t)(b * TTEXT + t0 + row)) * 256 + co0 + n * 16 + lr] = h;
                const float vq = bf2f(h);
                np = fmaf(vq, vq, np);
            }
            np += __shfl_xor(np, 1);
            np += __shfl_xor(np, 2);
            np += __shfl_xor(np, 4);
            np += __shfl_xor(np, 8);
            if (lr == 0) s_red[row][w] = np;
        }
        __syncthreads();
        if (tid < 16)
            tnorm[b * TTEXT + t0 + tid] = s_red[tid][0] + s_red[tid][1] + s_red[tid][2] + s_red[tid][3];
    } else {
        // ------------------------- feats stem -------------------------
        const int fb = bid - 40;
        const int b  = fb & 3;
        const int t0 = (fb >> 2) << 4;
        unsigned short* s_fin = s;          // [20][104]
        unsigned short* s_b1  = s + 2080;   // [18][264]
        unsigned short* s_b2  = s + 6832;   // [16][264]

        for (int idx = tid; idx < 20 * 24; idx += 256) {
            const int r  = idx / 24, c4 = idx - r * 24;
            const int ch = c4 * 4;
            const int x  = t0 - 2 + r;
            float4 v = {0.f, 0.f, 0.f, 0.f};
            if (ch < 80 && x >= 0 && x < TFEAT)
                v = *(const float4*)(feats + ((size_t)(b * TFEAT + x)) * 80 + ch);
            unsigned short* p = s_fin + r * 104 + ch;
            p[0] = f2bf(v.x); p[1] = f2bf(v.y); p[2] = f2bf(v.z); p[3] = f2bf(v.w);
        }
        __syncthreads();

        // f1: K=3, CINP=96 -> 9 chunks; compute 18 rows (2 M-frags, masked)
        f32x4 acc1[2][4];
#pragma unroll
        for (int m = 0; m < 2; ++m)
#pragma unroll
            for (int n = 0; n < 4; ++n) acc1[m][n] = {0.f, 0.f, 0.f, 0.f};
#pragma unroll 3
        for (int c = 0; c < 9; ++c) {
            const int k  = c / 3;
            const int ci = (c - k * 3) * 32 + koff;
            bf16x8 a[2];
#pragma unroll
            for (int m = 0; m < 2; ++m) {
                int rr = m * 16 + lr + k;
                if (rr > 19) rr = 19;   // clamp; rows >=18 are masked at write
                a[m] = *(const bf16x8*)(s_fin + rr * 104 + ci);
            }
#pragma unroll
            for (int n = 0; n < 4; ++n) {
                const bf16x8 bb = *(const bf16x8*)(wf1 + (((size_t)c * 256 + co0 + n * 16 + lr) << 5) + koff);
                acc1[0][n] = __builtin_amdgcn_mfma_f32_16x16x32_bf16(a[0], bb, acc1[0][n], 0, 0, 0);
                acc1[1][n] = __builtin_amdgcn_mfma_f32_16x16x32_bf16(a[1], bb, acc1[1][n], 0, 0, 0);
            }
        }
#pragma unroll
        for (int n = 0; n < 4; ++n) {
            const float bv = bf1v[co0 + n * 16 + lr];
#pragma unroll
            for (int m = 0; m < 2; ++m)
#pragma unroll
                for (int r = 0; r < 4; ++r) {
                    const int i = m * 16 + lk * 4 + r;
                    if (i < 18)
                        s_b1[i * 264 + co0 + n * 16 + lr] = f2bf(fmaxf(acc1[m][n][r] + bv, 0.f));
                }
        }
        __syncthreads();

        // f2: K=3, CIN=256 -> 24 chunks, A from s_b1 (row lr+k)
        f32x4 acc2[4];
#pragma unroll
        for (int n = 0; n < 4; ++n) acc2[n] = {0.f, 0.f, 0.f, 0.f};
#pragma unroll 4
        for (int c = 0; c < 24; ++c) {
            const int k  = c >> 3;
            const int ci = ((c & 7) << 5) + koff;
            const bf16x8 a = *(const bf16x8*)(s_b1 + (lr + k) * 264 + ci);
#pragma unroll
            for (int n = 0; n < 4; ++n) {
                const bf16x8 bb = *(const bf16x8*)(wf2 + (((size_t)c * 256 + co0 + n * 16 + lr) << 5) + koff);
                acc2[n] = __builtin_amdgcn_mfma_f32_16x16x32_bf16(a, bb, acc2[n], 0, 0, 0);
            }
        }
#pragma unroll
        for (int n = 0; n < 4; ++n) {
            const float bv = bf2v[co0 + n * 16 + lr];
#pragma unroll
            for (int r = 0; r < 4; ++r)
                s_b2[(lk * 4 + r) * 264 + co0 + n * 16 + lr] = f2bf(fmaxf(acc2[n][r] + bv, 0.f));
        }
        __syncthreads();

        // f3: K=1 -> 8 chunks, epilogue to global + norm
        f32x4 a3[4];
#pragma unroll
        for (int n = 0; n < 4; ++n) a3[n] = {0.f, 0.f, 0.f, 0.f};
#pragma unroll
        for (int c = 0; c < 8; ++c) {
            const bf16x8 a = *(const bf16x8*)(s_b2 + lr * 264 + (c << 5) + koff);
#pragma unroll
            for (int n = 0; n < 4; ++n) {
                const bf16x8 bb = *(const bf16x8*)(wf3 + (((size_t)c * 256 + co0 + n * 16 + lr) << 5) + koff);
                a3[n] = __builtin_amdgcn_mfma_f32_16x16x32_bf16(a, bb, a3[n], 0, 0, 0);
            }
        }
        float bv3[4];
#pragma unroll
        for (int n = 0; n < 4; ++n) bv3[n] = bf3v[co0 + n * 16 + lr];
#pragma unroll
        for (int r = 0; r < 4; ++r) {
            const int row = lk * 4 + r;
            float np = 0.f;
#pragma unroll
            for (int n = 0; n < 4; ++n) {
                const unsigned short h = f2bf(a3[n][r] + bv3[n]);
                fC[((size_t)(b * TFEAT + t0 + row)) * 256 + co0 + n * 16 + lr] = h;
                const float vq = bf2f(h);
                np = fmaf(vq, vq, np);
            }
            np += __shfl_xor(np, 1);
            np += __shfl_xor(np, 2);
            np += __shfl_xor(np, 4);
            np += __shfl_xor(np, 8);
            if (lr == 0) s_red[row][w] = np;
        }
        __syncthreads();
        if (tid < 16)
            fnorm[b * TFEAT + t0 + tid] = s_red[tid][0] + s_red[tid][1] + s_red[tid][2] + s_red[tid][3];
    }
}

// ---------------------------------------------------------------------------
// Score: one wave per 16 feats rows (grid 50 x 4 = 200 blocks), full 160-col
// rows per wave -> softmax is an in-wave 16-lane shfl reduction. Same verified
// math as round 2.
// ---------------------------------------------------------------------------
__global__ __launch_bounds__(64) void score_mfma(
    const unsigned short* __restrict__ F, const unsigned short* __restrict__ Tt,
    const float* __restrict__ fnorm, const float* __restrict__ tnorm,
    const unsigned char* __restrict__ xmask, const float* __restrict__ lg,
    float* __restrict__ out)
{
    const int b  = blockIdx.y;
    const int l  = threadIdx.x;
    const int lr = l & 15;
    const int lk = l >> 4;
    const int i0 = blockIdx.x * 16;

    f32x4 acc[10];
#pragma unroll
    for (int n = 0; n < 10; ++n) acc[n] = {0.f, 0.f, 0.f, 0.f};

    const unsigned short* __restrict__ Fp = F + ((size_t)(b * TFEAT + i0 + lr)) * 256;
    const unsigned short* __restrict__ Tp = Tt + ((size_t)b * TTEXT) * 256;

#pragma unroll 2
    for (int c = 0; c < 8; ++c) {
        const int d = c * 32 + lk * 8;
        const bf16x8 a = *(const bf16x8*)(Fp + d);
#pragma unroll
        for (int n = 0; n < 10; ++n) {
            const bf16x8 bb = *(const bf16x8*)(Tp + ((size_t)(n * 16 + lr)) * 256 + d);
            acc[n] = __builtin_amdgcn_mfma_f32_16x16x32_bf16(a, bb, acc[n], 0, 0, 0);
        }
    }

    float fn[4];
#pragma unroll
    for (int r = 0; r < 4; ++r) fn[r] = fnorm[b * TFEAT + i0 + lk * 4 + r];
    float tn[10]; bool mk[10];
#pragma unroll
    for (int n = 0; n < 10; ++n) {
        const int j = n * 16 + lr;
        tn[n] = tnorm[b * TTEXT + j];
        mk[n] = xmask[b * TTEXT + j] != 0;
    }
    float sc[10][4];
#pragma unroll
    for (int n = 0; n < 10; ++n)
#pragma unroll
        for (int r = 0; r < 4; ++r) {
            const float d2 = fn[r] + tn[n] - 2.0f * acc[n][r];
            const float sv = -sqrtf(fmaxf(d2, 0.0f));
            sc[n][r] = mk[n] ? -INFINITY : sv;
        }

    const float cst = lg[161] - lg[961] + lg[801];
#pragma unroll
    for (int r = 0; r < 4; ++r) {
        float mx = sc[0][r];
#pragma unroll
        for (int n = 1; n < 10; ++n) mx = fmaxf(mx, sc[n][r]);
        mx = fmaxf(mx, __shfl_xor(mx, 1));
        mx = fmaxf(mx, __shfl_xor(mx, 2));
        mx = fmaxf(mx, __shfl_xor(mx, 4));
        mx = fmaxf(mx, __shfl_xor(mx, 8));
        float sum = 0.f;
#pragma unroll
        for (int n = 0; n < 10; ++n) sum += expf(sc[n][r] - mx);
        sum += __shfl_xor(sum, 1);
        sum += __shfl_xor(sum, 2);
        sum += __shfl_xor(sum, 4);
        sum += __shfl_xor(sum, 8);
        const float lse = mx + logf(sum);

        const int row = i0 + lk * 4 + r;
        const float rowterm = cst - lg[row + 1] - lg[801 - row];
#pragma unroll
        for (int n = 0; n < 10; ++n) {
            const int j = n * 16 + lr;
            const float prior = rowterm - lg[j + 1] - lg[160 - j]
                              + lg[row + j + 1] + lg[960 - row - j];
            out[((size_t)(b * TFEAT + row)) * TTEXT + j] = sc[n][r] - lse + prior;
        }
    }
}

extern "C" void kernel_launch(void* const* d_in, const int* in_sizes, int n_in,
                              void* d_out, int out_size, void* d_ws, size_t ws_size,
                              hipStream_t stream) {
    const float* text  = (const float*)d_in[0];
    const float* feats = (const float*)d_in[1];
    const unsigned char* xmask = (const unsigned char*)d_in[4];
    const float* t_w1 = (const float*)d_in[5];
    const float* t_b1 = (const float*)d_in[6];
    const float* t_w2 = (const float*)d_in[7];
    const float* t_b2 = (const float*)d_in[8];
    const float* f_w1 = (const float*)d_in[9];
    const float* f_b1 = (const float*)d_in[10];
    const float* f_w2 = (const float*)d_in[11];
    const float* f_b2 = (const float*)d_in[12];
    const float* f_w3 = (const float*)d_in[13];
    const float* f_b3 = (const float*)d_in[14];
    float* out = (float*)d_out;

    char* wp = (char*)d_ws;
    auto alloc = [&](size_t bytes) -> void* {
        void* p = wp; wp += (bytes + 255) & ~(size_t)255; return p;
    };
    float* lg = (float*)alloc(1024 * 4);
    unsigned short* wb_t1 = (unsigned short*)alloc(196608 * 2);
    unsigned short* wb_t2 = (unsigned short*)alloc(65536 * 2);
    unsigned short* wb_f1 = (unsigned short*)alloc(73728 * 2);
    unsigned short* wb_f2 = (unsigned short*)alloc(196608 * 2);
    unsigned short* wb_f3 = (unsigned short*)alloc(65536 * 2);
    unsigned short* tB = (unsigned short*)alloc((size_t)NB * TTEXT * 256 * 2);
    unsigned short* fC = (unsigned short*)alloc((size_t)NB * TFEAT * 256 * 2);
    float* fnorm = (float*)alloc((size_t)NB * TFEAT * 4);
    float* tnorm = (float*)alloc((size_t)NB * TTEXT * 4);

    prep_kernel<<<dim3(768, 6), 256, 0, stream>>>(
        t_w1, t_w2, f_w1, f_w2, f_w3, wb_t1, wb_t2, wb_f1, wb_f2, wb_f3, lg);

    stems_kernel<<<240, 256, 0, stream>>>(
        text, feats,
        wb_t1, t_b1, wb_t2, t_b2,
        wb_f1, f_b1, wb_f2, f_b2, wb_f3, f_b3,
        tB, tnorm, fC, fnorm);

    score_mfma<<<dim3(50, NB), 64, 0, stream>>>(fC, tB, fnorm, tnorm, xmask, lg, out);
}